// Round 1
// baseline (420.882 us; speedup 1.0000x reference)
//
#include <hip/hip_runtime.h>
#include <hip/hip_bf16.h>

#define HW_P 32768   // H*W
#define HH 128
#define WW 256

// ---------------------------------------------------------------------------
// Kernel 1: fused QKV GEMM.
//   x  : (256, 32768)  channel-major (exactly the flat input x)
//   Q/K/V out: (32768, 256) pixel-major so per-pixel vectors are contiguous.
//   Q[p][o] = sum_c w[o][c] * x[c][p] + b[o]
// Tiling: 64 o x 64 p per block, K-step 16, thread computes 4x4, 3 acc sets.
// ---------------------------------------------------------------------------
__global__ __launch_bounds__(256) void qkv_gemm_k(
    const float* __restrict__ x,
    const float* __restrict__ wq, const float* __restrict__ wk, const float* __restrict__ wv,
    const float* __restrict__ bq, const float* __restrict__ bk, const float* __restrict__ bv,
    float* __restrict__ Q, float* __restrict__ K, float* __restrict__ V)
{
    __shared__ float Xs[16][64];   // [k][p]
    __shared__ float Wqs[16][64];  // [k][o] (transposed)
    __shared__ float Wks[16][64];
    __shared__ float Wvs[16][64];

    const int t  = threadIdx.x;
    const int tx = t & 15;   // p sub-tile
    const int ty = t >> 4;   // o sub-tile
    const int p0 = blockIdx.x * 64;
    const int o0 = blockIdx.y * 64;

    float accq[4][4] = {}, acck[4][4] = {}, accv[4][4] = {};

    const int lx_row = t >> 6;        // 0..3
    const int lx_col = t & 63;        // 0..63
    const int lw_o   = t >> 2;        // 0..63
    const int lw_k4  = (t & 3) * 4;   // 0,4,8,12

    for (int k0 = 0; k0 < 256; k0 += 16) {
        #pragma unroll
        for (int i = 0; i < 4; ++i) {
            const int kk = lx_row + 4 * i;
            Xs[kk][lx_col] = x[(k0 + kk) * HW_P + p0 + lx_col];
        }
        const float4 aq = *(const float4*)&wq[(o0 + lw_o) * 256 + k0 + lw_k4];
        const float4 ak = *(const float4*)&wk[(o0 + lw_o) * 256 + k0 + lw_k4];
        const float4 av = *(const float4*)&wv[(o0 + lw_o) * 256 + k0 + lw_k4];
        Wqs[lw_k4+0][lw_o] = aq.x; Wqs[lw_k4+1][lw_o] = aq.y;
        Wqs[lw_k4+2][lw_o] = aq.z; Wqs[lw_k4+3][lw_o] = aq.w;
        Wks[lw_k4+0][lw_o] = ak.x; Wks[lw_k4+1][lw_o] = ak.y;
        Wks[lw_k4+2][lw_o] = ak.z; Wks[lw_k4+3][lw_o] = ak.w;
        Wvs[lw_k4+0][lw_o] = av.x; Wvs[lw_k4+1][lw_o] = av.y;
        Wvs[lw_k4+2][lw_o] = av.z; Wvs[lw_k4+3][lw_o] = av.w;
        __syncthreads();

        #pragma unroll
        for (int kk = 0; kk < 16; ++kk) {
            const float4 b4 = *(const float4*)&Xs[kk][tx * 4];
            const float4 q4 = *(const float4*)&Wqs[kk][ty * 4];
            const float4 k4 = *(const float4*)&Wks[kk][ty * 4];
            const float4 v4 = *(const float4*)&Wvs[kk][ty * 4];
            const float bb[4] = {b4.x, b4.y, b4.z, b4.w};
            const float qa[4] = {q4.x, q4.y, q4.z, q4.w};
            const float ka[4] = {k4.x, k4.y, k4.z, k4.w};
            const float va[4] = {v4.x, v4.y, v4.z, v4.w};
            #pragma unroll
            for (int i = 0; i < 4; ++i)
                #pragma unroll
                for (int j = 0; j < 4; ++j) {
                    accq[i][j] = fmaf(qa[i], bb[j], accq[i][j]);
                    acck[i][j] = fmaf(ka[i], bb[j], acck[i][j]);
                    accv[i][j] = fmaf(va[i], bb[j], accv[i][j]);
                }
        }
        __syncthreads();
    }

    const float4 bq4 = *(const float4*)&bq[o0 + ty * 4];
    const float4 bk4 = *(const float4*)&bk[o0 + ty * 4];
    const float4 bv4 = *(const float4*)&bv[o0 + ty * 4];
    #pragma unroll
    for (int j = 0; j < 4; ++j) {
        const int p = p0 + tx * 4 + j;
        float4 oq = {accq[0][j] + bq4.x, accq[1][j] + bq4.y,
                     accq[2][j] + bq4.z, accq[3][j] + bq4.w};
        float4 ok = {acck[0][j] + bk4.x, acck[1][j] + bk4.y,
                     acck[2][j] + bk4.z, acck[3][j] + bk4.w};
        float4 ov = {accv[0][j] + bv4.x, accv[1][j] + bv4.y,
                     accv[2][j] + bv4.z, accv[3][j] + bv4.w};
        *(float4*)&Q[p * 256 + o0 + ty * 4] = oq;
        *(float4*)&K[p * 256 + o0 + ty * 4] = ok;
        *(float4*)&V[p * 256 + o0 + ty * 4] = ov;
    }
}

// ---------------------------------------------------------------------------
// Kernel 2: attention. One block per pixel, 256 threads = 1 per channel.
// ---------------------------------------------------------------------------
__global__ __launch_bounds__(256) void attn_k(
    const float* __restrict__ grid,   // (384, 768, 2)
    const float* __restrict__ Q, const float* __restrict__ K, const float* __restrict__ V,
    float* __restrict__ A)            // (32768, 256)
{
    __shared__ int   pk[9];
    __shared__ float sc[8][9];
    __shared__ float at[8][9];

    const int p = blockIdx.x;
    const int h = p >> 8;      // W = 256
    const int w = p & 255;
    const int c = threadIdx.x;

    if (c < 9) {
        const int kh = c / 3, kw = c - kh * 3;
        const int gr = (h * 3 + kh) * 768 + (w * 3 + kw);
        const float gx = grid[gr * 2 + 0];
        const float gy = grid[gr * 2 + 1];
        int ix = (int)rintf((gx + 1.0f) * 0.5f * 255.0f);
        int iy = (int)rintf((gy + 1.0f) * 0.5f * 127.0f);
        ix = min(max(ix, 0), 255);
        iy = min(max(iy, 0), 127);
        pk[c] = iy * 256 + ix;
    }
    __syncthreads();

    const float qv = Q[p * 256 + c];
    const int head = c >> 5;
    float vreg[9];

    #pragma unroll
    for (int k = 0; k < 9; ++k) {
        const int pkk = pk[k];
        const float kv = K[pkk * 256 + c];
        vreg[k] = V[pkk * 256 + c];
        float d = qv * kv;
        d += __shfl_xor(d, 1);
        d += __shfl_xor(d, 2);
        d += __shfl_xor(d, 4);
        d += __shfl_xor(d, 8);
        d += __shfl_xor(d, 16);
        if ((c & 31) == 0) sc[head][k] = d;
    }
    __syncthreads();

    if (c < 8) {
        const float scale = 0.17677669529663687f;  // 32^-0.5
        float s[9], m = -1e30f;
        #pragma unroll
        for (int k = 0; k < 9; ++k) { s[k] = sc[c][k] * scale; m = fmaxf(m, s[k]); }
        float sum = 0.0f;
        #pragma unroll
        for (int k = 0; k < 9; ++k) { s[k] = expf(s[k] - m); sum += s[k]; }
        const float inv = 1.0f / sum;
        #pragma unroll
        for (int k = 0; k < 9; ++k) at[c][k] = s[k] * inv;
    }
    __syncthreads();

    float o = 0.0f;
    #pragma unroll
    for (int k = 0; k < 9; ++k) o = fmaf(at[head][k], vreg[k], o);
    A[p * 256 + c] = o;
}

// ---------------------------------------------------------------------------
// Kernel 3: output GEMM. y[o][p] = sum_c wo[o][c] * A[p][c] + bo[o]
// ---------------------------------------------------------------------------
__global__ __launch_bounds__(256) void out_gemm_k(
    const float* __restrict__ A,      // (32768, 256)
    const float* __restrict__ wo, const float* __restrict__ bo,
    float* __restrict__ y)            // (256, 32768)
{
    __shared__ float As[16][64];  // [c][p]
    __shared__ float Ws[16][64];  // [c][o]

    const int t  = threadIdx.x;
    const int tx = t & 15;   // p
    const int ty = t >> 4;   // o
    const int p0 = blockIdx.x * 64;
    const int o0 = blockIdx.y * 64;

    float acc[4][4] = {};

    const int l_r  = t >> 2;        // 0..63
    const int l_c4 = (t & 3) * 4;   // 0,4,8,12

    for (int c0 = 0; c0 < 256; c0 += 16) {
        const float4 a4 = *(const float4*)&A[(p0 + l_r) * 256 + c0 + l_c4];
        const float4 w4 = *(const float4*)&wo[(o0 + l_r) * 256 + c0 + l_c4];
        As[l_c4+0][l_r] = a4.x; As[l_c4+1][l_r] = a4.y;
        As[l_c4+2][l_r] = a4.z; As[l_c4+3][l_r] = a4.w;
        Ws[l_c4+0][l_r] = w4.x; Ws[l_c4+1][l_r] = w4.y;
        Ws[l_c4+2][l_r] = w4.z; Ws[l_c4+3][l_r] = w4.w;
        __syncthreads();

        #pragma unroll
        for (int cc = 0; cc < 16; ++cc) {
            const float4 av4 = *(const float4*)&As[cc][tx * 4];
            const float4 wv4 = *(const float4*)&Ws[cc][ty * 4];
            const float ab[4] = {av4.x, av4.y, av4.z, av4.w};
            const float wb[4] = {wv4.x, wv4.y, wv4.z, wv4.w};
            #pragma unroll
            for (int i = 0; i < 4; ++i)
                #pragma unroll
                for (int j = 0; j < 4; ++j)
                    acc[i][j] = fmaf(wb[i], ab[j], acc[i][j]);
        }
        __syncthreads();
    }

    #pragma unroll
    for (int i = 0; i < 4; ++i) {
        const int o = o0 + ty * 4 + i;
        const float b = bo[o];
        float4 ov = {acc[i][0] + b, acc[i][1] + b, acc[i][2] + b, acc[i][3] + b};
        *(float4*)&y[o * HW_P + p0 + tx * 4] = ov;
    }
}

extern "C" void kernel_launch(void* const* d_in, const int* in_sizes, int n_in,
                              void* d_out, int out_size, void* d_ws, size_t ws_size,
                              hipStream_t stream) {
    const float* x    = (const float*)d_in[0];
    const float* grid = (const float*)d_in[1];
    const float* wq   = (const float*)d_in[2];
    const float* bq   = (const float*)d_in[3];
    const float* wk   = (const float*)d_in[4];
    const float* bk   = (const float*)d_in[5];
    const float* wv   = (const float*)d_in[6];
    const float* bv   = (const float*)d_in[7];
    const float* wo   = (const float*)d_in[8];
    const float* bo   = (const float*)d_in[9];
    float* y = (float*)d_out;

    float* Q = (float*)d_ws;              // 32768*256 fp32 = 32 MB
    float* K = Q + (size_t)HW_P * 256;
    float* V = K + (size_t)HW_P * 256;
    float* A = V + (size_t)HW_P * 256;    // total 128 MB workspace

    dim3 gg(HW_P / 64, 4), bb(256);
    qkv_gemm_k<<<gg, bb, 0, stream>>>(x, wq, wk, wv, bq, bk, bv, Q, K, V);
    attn_k<<<HW_P, 256, 0, stream>>>(grid, Q, K, V, A);
    out_gemm_k<<<gg, bb, 0, stream>>>(A, wo, bo, y);
}

// Round 2
// 241.632 us; speedup vs baseline: 1.7418x; 1.7418x over previous
//
#include <hip/hip_runtime.h>
#include <hip/hip_bf16.h>

#define P_TOT 32768   // H*W
#define O_QKV 768

using f32x4  = float  __attribute__((ext_vector_type(4)));
using bf16x8 = __bf16 __attribute__((ext_vector_type(8)));

typedef __attribute__((address_space(1))) void* gptr_t;
typedef __attribute__((address_space(3))) void* sptr_t;
// async global->LDS, 16B per lane, dest = uniform base + lane*16
#define GLL16(g, l) __builtin_amdgcn_global_load_lds((gptr_t)(g), (sptr_t)(l), 16, 0, 0)

__device__ __forceinline__ ushort f2b(float f) {
    __hip_bfloat16 h = __float2bfloat16(f);   // RNE
    return *reinterpret_cast<ushort*>(&h);
}
__device__ __forceinline__ float b2f(ushort u) {
    return __uint_as_float(((unsigned)u) << 16);   // exact
}

// ---------------------------------------------------------------------------
// prep: cast weights to bf16 (Wqkv = [wq;wk;wv] rows, (768,256)), pack biases
// ---------------------------------------------------------------------------
__global__ __launch_bounds__(256) void prep_w(
    const float* __restrict__ wq, const float* __restrict__ wk,
    const float* __restrict__ wv, const float* __restrict__ wo,
    const float* __restrict__ bq, const float* __restrict__ bk,
    const float* __restrict__ bv,
    ushort* __restrict__ Wqkv, ushort* __restrict__ Wo, float* __restrict__ Bqkv)
{
    const int i = blockIdx.x * 256 + threadIdx.x;   // grid 256 -> i < 65536
    Wqkv[i]           = f2b(wq[i]);
    Wqkv[65536 + i]   = f2b(wk[i]);
    Wqkv[131072 + i]  = f2b(wv[i]);
    Wo[i]             = f2b(wo[i]);
    if (i < 256) { Bqkv[i] = bq[i]; Bqkv[256 + i] = bk[i]; Bqkv[512 + i] = bv[i]; }
}

// ---------------------------------------------------------------------------
// transpose: x (256, 32768) fp32 -> Xt (32768, 256) bf16
// ---------------------------------------------------------------------------
__global__ __launch_bounds__(256) void transpose_x(
    const float* __restrict__ x, ushort* __restrict__ Xt)
{
    __shared__ float ts[64][65];
    const int p0 = blockIdx.x * 64, c0 = blockIdx.y * 64;
    const int t = threadIdx.x;
    const int pl = t & 63, cl = t >> 6;
    #pragma unroll
    for (int i = 0; i < 16; ++i)
        ts[cl + 4 * i][pl] = x[(size_t)(c0 + cl + 4 * i) * P_TOT + p0 + pl];
    __syncthreads();
    const int pr = t >> 4, cc = (t & 15) * 4;
    #pragma unroll
    for (int i = 0; i < 4; ++i) {
        const int p = pr + 16 * i;
        ushort4 u;
        u.x = f2b(ts[cc + 0][p]); u.y = f2b(ts[cc + 1][p]);
        u.z = f2b(ts[cc + 2][p]); u.w = f2b(ts[cc + 3][p]);
        *(ushort4*)&Xt[(size_t)(p0 + p) * 256 + c0 + cc] = u;
    }
}

// ---------------------------------------------------------------------------
// GEMM1: QKV[p][o] = sum_c Xt[p][c] * Wqkv[o][c] + Bqkv[o]   (BT form)
// M = p (A = Xt), N = o (B = Wqkv), K = 256. 128x128 tile, BK=32, 4 waves.
// ---------------------------------------------------------------------------
__global__ __launch_bounds__(256) void gemm_qkv(
    ushort* __restrict__ Xt, ushort* __restrict__ Wqkv,
    const float* __restrict__ Bqkv, ushort* __restrict__ QKV)
{
    __shared__ __align__(16) ushort As[128 * 32];
    __shared__ __align__(16) ushort Bs[128 * 32];

    const int t    = threadIdx.x;
    const int lane = t & 63;
    const int w    = t >> 6;
    const int m0   = blockIdx.x * 128;   // p
    const int n0   = blockIdx.y * 128;   // o
    const int wm   = (w & 1) * 64;
    const int wn   = (w >> 1) * 64;
    const int l16  = lane & 15;
    const int quad = lane >> 4;
    const int srow = lane >> 2;          // staging: 4 lanes per 64B row-chunk
    const int scol = (lane & 3) * 8;     // elements

    f32x4 acc[4][4] = {};

    for (int k0 = 0; k0 < 256; k0 += 32) {
        #pragma unroll
        for (int j = 0; j < 2; ++j) {
            const int i = w * 2 + j;     // 1KB chunk = 16 rows x 64B
            GLL16(Xt   + (size_t)(m0 + i * 16 + srow) * 256 + k0 + scol, As + i * 512);
            GLL16(Wqkv + (size_t)(n0 + i * 16 + srow) * 256 + k0 + scol, Bs + i * 512);
        }
        __syncthreads();
        bf16x8 af[4], bfr[4];
        #pragma unroll
        for (int mi = 0; mi < 4; ++mi)
            af[mi] = *(const bf16x8*)(As + (wm + mi * 16 + l16) * 32 + quad * 8);
        #pragma unroll
        for (int ni = 0; ni < 4; ++ni)
            bfr[ni] = *(const bf16x8*)(Bs + (wn + ni * 16 + l16) * 32 + quad * 8);
        #pragma unroll
        for (int mi = 0; mi < 4; ++mi)
            #pragma unroll
            for (int ni = 0; ni < 4; ++ni)
                acc[mi][ni] = __builtin_amdgcn_mfma_f32_16x16x32_bf16(
                    af[mi], bfr[ni], acc[mi][ni], 0, 0, 0);
        __syncthreads();
    }

    #pragma unroll
    for (int ni = 0; ni < 4; ++ni) {
        const int og = n0 + wn + ni * 16 + l16;
        const float bias = Bqkv[og];
        #pragma unroll
        for (int mi = 0; mi < 4; ++mi)
            #pragma unroll
            for (int r = 0; r < 4; ++r) {
                const int pg = m0 + wm + mi * 16 + quad * 4 + r;
                QKV[(size_t)pg * O_QKV + og] = f2b(acc[mi][ni][r] + bias);
            }
    }
}

// ---------------------------------------------------------------------------
// attention: one block per pixel, 256 threads = 1 per channel (bf16 I/O)
// ---------------------------------------------------------------------------
__global__ __launch_bounds__(256) void attn_k(
    const float* __restrict__ grid, const ushort* __restrict__ QKV,
    ushort* __restrict__ Ab)
{
    __shared__ int   pk[9];
    __shared__ float sc[8][9];
    __shared__ float at[8][9];

    const int p = blockIdx.x;
    const int h = p >> 8;
    const int w = p & 255;
    const int c = threadIdx.x;

    if (c < 9) {
        const int kh = c / 3, kw = c - kh * 3;
        const int gr = (h * 3 + kh) * 768 + (w * 3 + kw);
        const float gx = grid[gr * 2 + 0];
        const float gy = grid[gr * 2 + 1];
        int ix = (int)rintf((gx + 1.0f) * 0.5f * 255.0f);
        int iy = (int)rintf((gy + 1.0f) * 0.5f * 127.0f);
        ix = min(max(ix, 0), 255);
        iy = min(max(iy, 0), 127);
        pk[c] = iy * 256 + ix;
    }
    __syncthreads();

    const float qv = b2f(QKV[(size_t)p * O_QKV + c]);
    const int head = c >> 5;
    float vreg[9];

    #pragma unroll
    for (int k = 0; k < 9; ++k) {
        const size_t base = (size_t)pk[k] * O_QKV;
        const float kv = b2f(QKV[base + 256 + c]);
        vreg[k] = b2f(QKV[base + 512 + c]);
        float d = qv * kv;
        d += __shfl_xor(d, 1);
        d += __shfl_xor(d, 2);
        d += __shfl_xor(d, 4);
        d += __shfl_xor(d, 8);
        d += __shfl_xor(d, 16);
        if ((c & 31) == 0) sc[head][k] = d;
    }
    __syncthreads();

    if (c < 8) {
        const float scale = 0.17677669529663687f;  // 32^-0.5
        float s[9], m = -1e30f;
        #pragma unroll
        for (int k = 0; k < 9; ++k) { s[k] = sc[c][k] * scale; m = fmaxf(m, s[k]); }
        float sum = 0.0f;
        #pragma unroll
        for (int k = 0; k < 9; ++k) { s[k] = expf(s[k] - m); sum += s[k]; }
        const float inv = 1.0f / sum;
        #pragma unroll
        for (int k = 0; k < 9; ++k) at[c][k] = s[k] * inv;
    }
    __syncthreads();

    float o = 0.0f;
    #pragma unroll
    for (int k = 0; k < 9; ++k) o = fmaf(at[head][k], vreg[k], o);
    Ab[(size_t)p * 256 + c] = f2b(o);
}

// ---------------------------------------------------------------------------
// GEMM2: y[o][p] = sum_c Wo[o][c] * Ab[p][c] + bo[o]
// M = o (A = Wo), N = p (B = Ab). Output fp32 (256, 32768).
// ---------------------------------------------------------------------------
__global__ __launch_bounds__(256) void gemm_out(
    ushort* __restrict__ Wo, ushort* __restrict__ Ab,
    const float* __restrict__ bo, float* __restrict__ y)
{
    __shared__ __align__(16) ushort As[128 * 32];
    __shared__ __align__(16) ushort Bs[128 * 32];

    const int t    = threadIdx.x;
    const int lane = t & 63;
    const int w    = t >> 6;
    const int m0   = blockIdx.y * 128;   // o
    const int n0   = blockIdx.x * 128;   // p
    const int wm   = (w & 1) * 64;
    const int wn   = (w >> 1) * 64;
    const int l16  = lane & 15;
    const int quad = lane >> 4;
    const int srow = lane >> 2;
    const int scol = (lane & 3) * 8;

    f32x4 acc[4][4] = {};

    for (int k0 = 0; k0 < 256; k0 += 32) {
        #pragma unroll
        for (int j = 0; j < 2; ++j) {
            const int i = w * 2 + j;
            GLL16(Wo + (size_t)(m0 + i * 16 + srow) * 256 + k0 + scol, As + i * 512);
            GLL16(Ab + (size_t)(n0 + i * 16 + srow) * 256 + k0 + scol, Bs + i * 512);
        }
        __syncthreads();
        bf16x8 af[4], bfr[4];
        #pragma unroll
        for (int mi = 0; mi < 4; ++mi)
            af[mi] = *(const bf16x8*)(As + (wm + mi * 16 + l16) * 32 + quad * 8);
        #pragma unroll
        for (int ni = 0; ni < 4; ++ni)
            bfr[ni] = *(const bf16x8*)(Bs + (wn + ni * 16 + l16) * 32 + quad * 8);
        #pragma unroll
        for (int mi = 0; mi < 4; ++mi)
            #pragma unroll
            for (int ni = 0; ni < 4; ++ni)
                acc[mi][ni] = __builtin_amdgcn_mfma_f32_16x16x32_bf16(
                    af[mi], bfr[ni], acc[mi][ni], 0, 0, 0);
        __syncthreads();
    }

    #pragma unroll
    for (int mi = 0; mi < 4; ++mi)
        #pragma unroll
        for (int r = 0; r < 4; ++r) {
            const int og = m0 + wm + mi * 16 + quad * 4 + r;
            const float bias = bo[og];
            #pragma unroll
            for (int ni = 0; ni < 4; ++ni) {
                const int pg = n0 + wn + ni * 16 + l16;
                y[(size_t)og * P_TOT + pg] = acc[mi][ni][r] + bias;
            }
        }
}

extern "C" void kernel_launch(void* const* d_in, const int* in_sizes, int n_in,
                              void* d_out, int out_size, void* d_ws, size_t ws_size,
                              hipStream_t stream) {
    const float* x    = (const float*)d_in[0];
    const float* grid = (const float*)d_in[1];
    const float* wq   = (const float*)d_in[2];
    const float* bq   = (const float*)d_in[3];
    const float* wk   = (const float*)d_in[4];
    const float* bk   = (const float*)d_in[5];
    const float* wv   = (const float*)d_in[6];
    const float* bv   = (const float*)d_in[7];
    const float* wo   = (const float*)d_in[8];
    const float* bo   = (const float*)d_in[9];
    float* y = (float*)d_out;

    ushort* Xt   = (ushort*)d_ws;                       // 16 MB
    ushort* QKV  = Xt  + (size_t)P_TOT * 256;           // 48 MB
    ushort* Ab   = QKV + (size_t)P_TOT * O_QKV;         // 16 MB
    ushort* Wqkv = Ab  + (size_t)P_TOT * 256;           // 384 KB
    ushort* Wo   = Wqkv + 768 * 256;                    // 128 KB
    float*  Bqkv = (float*)(Wo + 256 * 256);            // 3 KB

    prep_w<<<256, 256, 0, stream>>>(wq, wk, wv, wo, bq, bk, bv, Wqkv, Wo, Bqkv);
    transpose_x<<<dim3(P_TOT / 64, 4), 256, 0, stream>>>(x, Xt);
    gemm_qkv<<<dim3(P_TOT / 128, O_QKV / 128), 256, 0, stream>>>(Xt, Wqkv, Bqkv, QKV);
    attn_k<<<P_TOT, 256, 0, stream>>>(grid, QKV, Ab);
    gemm_out<<<dim3(P_TOT / 128, 2), 256, 0, stream>>>(Wo, Ab, bo, y);
}

// Round 3
// 183.616 us; speedup vs baseline: 2.2922x; 1.3160x over previous
//
#include <hip/hip_runtime.h>
#include <hip/hip_bf16.h>

#define P_TOT 32768   // H*W
#define O_QKV 768

using f32x4   = float  __attribute__((ext_vector_type(4)));
using bf16x8  = __bf16 __attribute__((ext_vector_type(8)));
using ushort8 = unsigned short __attribute__((ext_vector_type(8)));

typedef __attribute__((address_space(1))) void* gptr_t;
typedef __attribute__((address_space(3))) void* sptr_t;
// async global->LDS, 16B per lane, dest = uniform base + lane*16
#define GLL16(g, l) __builtin_amdgcn_global_load_lds((gptr_t)(g), (sptr_t)(l), 16, 0, 0)

__device__ __forceinline__ ushort f2b(float f) {
    __hip_bfloat16 h = __float2bfloat16(f);   // RNE
    return *reinterpret_cast<ushort*>(&h);
}
__device__ __forceinline__ float b2f(ushort u) {
    return __uint_as_float(((unsigned)u) << 16);   // exact
}

// ---------------------------------------------------------------------------
// prep: cast weights to bf16 (Wqkv = [wq;wk;wv] rows, (768,256)), pack biases
// ---------------------------------------------------------------------------
__global__ __launch_bounds__(256) void prep_w(
    const float* __restrict__ wq, const float* __restrict__ wk,
    const float* __restrict__ wv, const float* __restrict__ wo,
    const float* __restrict__ bq, const float* __restrict__ bk,
    const float* __restrict__ bv,
    ushort* __restrict__ Wqkv, ushort* __restrict__ Wo, float* __restrict__ Bqkv)
{
    const int i = blockIdx.x * 256 + threadIdx.x;   // grid 256 -> i < 65536
    Wqkv[i]           = f2b(wq[i]);
    Wqkv[65536 + i]   = f2b(wk[i]);
    Wqkv[131072 + i]  = f2b(wv[i]);
    Wo[i]             = f2b(wo[i]);
    if (i < 256) { Bqkv[i] = bq[i]; Bqkv[256 + i] = bk[i]; Bqkv[512 + i] = bv[i]; }
}

// ---------------------------------------------------------------------------
// transpose: x (256, 32768) fp32 -> Xt (32768, 256) bf16
// ---------------------------------------------------------------------------
__global__ __launch_bounds__(256) void transpose_x(
    const float* __restrict__ x, ushort* __restrict__ Xt)
{
    __shared__ float ts[64][65];
    const int p0 = blockIdx.x * 64, c0 = blockIdx.y * 64;
    const int t = threadIdx.x;
    const int pl = t & 63, cl = t >> 6;
    #pragma unroll
    for (int i = 0; i < 16; ++i)
        ts[cl + 4 * i][pl] = x[(size_t)(c0 + cl + 4 * i) * P_TOT + p0 + pl];
    __syncthreads();
    const int pr = t >> 4, cc = (t & 15) * 4;
    #pragma unroll
    for (int i = 0; i < 4; ++i) {
        const int p = pr + 16 * i;
        ushort4 u;
        u.x = f2b(ts[cc + 0][p]); u.y = f2b(ts[cc + 1][p]);
        u.z = f2b(ts[cc + 2][p]); u.w = f2b(ts[cc + 3][p]);
        *(ushort4*)&Xt[(size_t)(p0 + p) * 256 + c0 + cc] = u;
    }
}

// ---------------------------------------------------------------------------
// GEMM1: QKV[p][o] = sum_c Xt[p][c] * Wqkv[o][c] + Bqkv[o]   (BT form)
// ---------------------------------------------------------------------------
__global__ __launch_bounds__(256) void gemm_qkv(
    ushort* __restrict__ Xt, ushort* __restrict__ Wqkv,
    const float* __restrict__ Bqkv, ushort* __restrict__ QKV)
{
    __shared__ __align__(16) ushort As[128 * 32];
    __shared__ __align__(16) ushort Bs[128 * 32];

    const int t    = threadIdx.x;
    const int lane = t & 63;
    const int w    = t >> 6;
    const int m0   = blockIdx.x * 128;   // p
    const int n0   = blockIdx.y * 128;   // o
    const int wm   = (w & 1) * 64;
    const int wn   = (w >> 1) * 64;
    const int l16  = lane & 15;
    const int quad = lane >> 4;
    const int srow = lane >> 2;
    const int scol = (lane & 3) * 8;

    f32x4 acc[4][4] = {};

    for (int k0 = 0; k0 < 256; k0 += 32) {
        #pragma unroll
        for (int j = 0; j < 2; ++j) {
            const int i = w * 2 + j;
            GLL16(Xt   + (size_t)(m0 + i * 16 + srow) * 256 + k0 + scol, As + i * 512);
            GLL16(Wqkv + (size_t)(n0 + i * 16 + srow) * 256 + k0 + scol, Bs + i * 512);
        }
        __syncthreads();
        bf16x8 af[4], bfr[4];
        #pragma unroll
        for (int mi = 0; mi < 4; ++mi)
            af[mi] = *(const bf16x8*)(As + (wm + mi * 16 + l16) * 32 + quad * 8);
        #pragma unroll
        for (int ni = 0; ni < 4; ++ni)
            bfr[ni] = *(const bf16x8*)(Bs + (wn + ni * 16 + l16) * 32 + quad * 8);
        #pragma unroll
        for (int mi = 0; mi < 4; ++mi)
            #pragma unroll
            for (int ni = 0; ni < 4; ++ni)
                acc[mi][ni] = __builtin_amdgcn_mfma_f32_16x16x32_bf16(
                    af[mi], bfr[ni], acc[mi][ni], 0, 0, 0);
        __syncthreads();
    }

    #pragma unroll
    for (int ni = 0; ni < 4; ++ni) {
        const int og = n0 + wn + ni * 16 + l16;
        const float bias = Bqkv[og];
        #pragma unroll
        for (int mi = 0; mi < 4; ++mi)
            #pragma unroll
            for (int r = 0; r < 4; ++r) {
                const int pg = m0 + wm + mi * 16 + quad * 4 + r;
                QKV[(size_t)pg * O_QKV + og] = f2b(acc[mi][ni][r] + bias);
            }
    }
}

// ---------------------------------------------------------------------------
// attention: 8 pixels per 256-thread block; thread = (pixel, 8-channel group).
// All 18 K/V 16B gathers issued up front -> latency hidden.
// ---------------------------------------------------------------------------
__global__ __launch_bounds__(256) void attn_k(
    const float* __restrict__ grid, const ushort* __restrict__ QKV,
    ushort* __restrict__ Ab)
{
    __shared__ int   pk[8][9];
    __shared__ float sc[8][8][9];
    __shared__ float at[8][8][9];

    const int t  = threadIdx.x;
    const int p0 = blockIdx.x * 8;

    if (t < 72) {
        const int pix = t / 9, k = t - pix * 9;
        const int p = p0 + pix;
        const int h = p >> 8, w = p & 255;
        const int kh = k / 3, kw = k - kh * 3;
        const int gr = (h * 3 + kh) * 768 + (w * 3 + kw);
        const float gx = grid[gr * 2 + 0];
        const float gy = grid[gr * 2 + 1];
        int ix = (int)rintf((gx + 1.0f) * 0.5f * 255.0f);
        int iy = (int)rintf((gy + 1.0f) * 0.5f * 127.0f);
        ix = min(max(ix, 0), 255);
        iy = min(max(iy, 0), 127);
        pk[pix][k] = iy * 256 + ix;
    }
    __syncthreads();

    const int pix  = t >> 5;        // 0..7
    const int g    = t & 31;        // channel group
    const int sub  = g & 3;
    const int head = g >> 2;
    const int p    = p0 + pix;
    const int c8   = g * 8;

    const ushort8 q8 = *(const ushort8*)&QKV[(size_t)p * O_QKV + c8];

    ushort8 k8[9], v8[9];
    #pragma unroll
    for (int k = 0; k < 9; ++k) {
        const size_t base = (size_t)pk[pix][k] * O_QKV + c8;
        k8[k] = *(const ushort8*)&QKV[base + 256];
        v8[k] = *(const ushort8*)&QKV[base + 512];
    }

    #pragma unroll
    for (int k = 0; k < 9; ++k) {
        float d = 0.0f;
        #pragma unroll
        for (int i = 0; i < 8; ++i) d = fmaf(b2f(q8[i]), b2f(k8[k][i]), d);
        d += __shfl_xor(d, 1);
        d += __shfl_xor(d, 2);
        if (sub == 0) sc[pix][head][k] = d;
    }
    __syncthreads();

    if (t < 64) {
        const int px = t >> 3, hd = t & 7;
        const float scale = 0.17677669529663687f;  // 32^-0.5
        float s[9], m = -1e30f;
        #pragma unroll
        for (int k = 0; k < 9; ++k) { s[k] = sc[px][hd][k] * scale; m = fmaxf(m, s[k]); }
        float sum = 0.0f;
        #pragma unroll
        for (int k = 0; k < 9; ++k) { s[k] = expf(s[k] - m); sum += s[k]; }
        const float inv = 1.0f / sum;
        #pragma unroll
        for (int k = 0; k < 9; ++k) at[px][hd][k] = s[k] * inv;
    }
    __syncthreads();

    float o[8] = {};
    #pragma unroll
    for (int k = 0; k < 9; ++k) {
        const float a = at[pix][head][k];
        #pragma unroll
        for (int i = 0; i < 8; ++i) o[i] = fmaf(a, b2f(v8[k][i]), o[i]);
    }
    ushort8 r;
    #pragma unroll
    for (int i = 0; i < 8; ++i) r[i] = f2b(o[i]);
    *(ushort8*)&Ab[(size_t)p * 256 + c8] = r;
}

// ---------------------------------------------------------------------------
// GEMM2: y[o][p] = sum_c Wo[o][c] * Ab[p][c] + bo[o]
// ---------------------------------------------------------------------------
__global__ __launch_bounds__(256) void gemm_out(
    ushort* __restrict__ Wo, ushort* __restrict__ Ab,
    const float* __restrict__ bo, float* __restrict__ y)
{
    __shared__ __align__(16) ushort As[128 * 32];
    __shared__ __align__(16) ushort Bs[128 * 32];

    const int t    = threadIdx.x;
    const int lane = t & 63;
    const int w    = t >> 6;
    const int m0   = blockIdx.y * 128;   // o
    const int n0   = blockIdx.x * 128;   // p
    const int wm   = (w & 1) * 64;
    const int wn   = (w >> 1) * 64;
    const int l16  = lane & 15;
    const int quad = lane >> 4;
    const int srow = lane >> 2;
    const int scol = (lane & 3) * 8;

    f32x4 acc[4][4] = {};

    for (int k0 = 0; k0 < 256; k0 += 32) {
        #pragma unroll
        for (int j = 0; j < 2; ++j) {
            const int i = w * 2 + j;
            GLL16(Wo + (size_t)(m0 + i * 16 + srow) * 256 + k0 + scol, As + i * 512);
            GLL16(Ab + (size_t)(n0 + i * 16 + srow) * 256 + k0 + scol, Bs + i * 512);
        }
        __syncthreads();
        bf16x8 af[4], bfr[4];
        #pragma unroll
        for (int mi = 0; mi < 4; ++mi)
            af[mi] = *(const bf16x8*)(As + (wm + mi * 16 + l16) * 32 + quad * 8);
        #pragma unroll
        for (int ni = 0; ni < 4; ++ni)
            bfr[ni] = *(const bf16x8*)(Bs + (wn + ni * 16 + l16) * 32 + quad * 8);
        #pragma unroll
        for (int mi = 0; mi < 4; ++mi)
            #pragma unroll
            for (int ni = 0; ni < 4; ++ni)
                acc[mi][ni] = __builtin_amdgcn_mfma_f32_16x16x32_bf16(
                    af[mi], bfr[ni], acc[mi][ni], 0, 0, 0);
        __syncthreads();
    }

    #pragma unroll
    for (int mi = 0; mi < 4; ++mi)
        #pragma unroll
        for (int r = 0; r < 4; ++r) {
            const int og = m0 + wm + mi * 16 + quad * 4 + r;
            const float bias = bo[og];
            #pragma unroll
            for (int ni = 0; ni < 4; ++ni) {
                const int pg = n0 + wn + ni * 16 + l16;
                y[(size_t)og * P_TOT + pg] = acc[mi][ni][r] + bias;
            }
        }
}

extern "C" void kernel_launch(void* const* d_in, const int* in_sizes, int n_in,
                              void* d_out, int out_size, void* d_ws, size_t ws_size,
                              hipStream_t stream) {
    const float* x    = (const float*)d_in[0];
    const float* grid = (const float*)d_in[1];
    const float* wq   = (const float*)d_in[2];
    const float* bq   = (const float*)d_in[3];
    const float* wk   = (const float*)d_in[4];
    const float* bk   = (const float*)d_in[5];
    const float* wv   = (const float*)d_in[6];
    const float* bv   = (const float*)d_in[7];
    const float* wo   = (const float*)d_in[8];
    const float* bo   = (const float*)d_in[9];
    float* y = (float*)d_out;

    ushort* Xt   = (ushort*)d_ws;                       // 16 MB
    ushort* QKV  = Xt  + (size_t)P_TOT * 256;           // 48 MB
    ushort* Ab   = QKV + (size_t)P_TOT * O_QKV;         // 16 MB
    ushort* Wqkv = Ab  + (size_t)P_TOT * 256;           // 384 KB
    ushort* Wo   = Wqkv + 768 * 256;                    // 128 KB
    float*  Bqkv = (float*)(Wo + 256 * 256);            // 3 KB

    prep_w<<<256, 256, 0, stream>>>(wq, wk, wv, wo, bq, bk, bv, Wqkv, Wo, Bqkv);
    transpose_x<<<dim3(P_TOT / 64, 4), 256, 0, stream>>>(x, Xt);
    gemm_qkv<<<dim3(P_TOT / 128, O_QKV / 128), 256, 0, stream>>>(Xt, Wqkv, Bqkv, QKV);
    attn_k<<<P_TOT / 8, 256, 0, stream>>>(grid, QKV, Ab);
    gemm_out<<<dim3(P_TOT / 128, 2), 256, 0, stream>>>(Wo, Ab, bo, y);
}